// Round 1
// baseline (260.178 us; speedup 1.0000x reference)
//
#include <hip/hip_runtime.h>
#include <hip/hip_bf16.h>
#include <math.h>

constexpr int B_   = 8;
constexpr int N_   = 2048;
constexpr int FIN  = 256;
constexpr int FOUT = 128;

constexpr int CH  = 512;          // KB K-chunk length
constexpr int NCH = N_ / CH;      // 4 chunks
constexpr int PR  = CH + 8;       // 520 shorts per P row (pad)
constexpr int XR  = FIN + 8;      // 264 shorts per xs row (pad)
constexpr int TR  = 40;           // ka transpose-tile row stride (32 j + 8 pad)

typedef __attribute__((ext_vector_type(8))) short bf16x8;
typedef __attribute__((ext_vector_type(4))) float f32x4;
typedef __attribute__((ext_vector_type(4))) int   i32x4;

static __device__ __forceinline__ unsigned short f2bf(float f) {
    __hip_bfloat16 h = __float2bfloat16(f);
    return *reinterpret_cast<unsigned short*>(&h);
}
static __device__ __forceinline__ i32x4 ntload4(const int* p) {
    return __builtin_nontemporal_load((const i32x4*)p);
}

// ---------------------------------------------------------------------------
// K0: Wt[n][k] = bf16(W[k][n])  (dim-major weight, 64 KB). Tiny.
// ---------------------------------------------------------------------------
__global__ __launch_bounds__(256) void k0_wt(const float* __restrict__ W,
                                             unsigned short* __restrict__ Wt) {
    const int n = blockIdx.x;   // 0..127
    const int k = threadIdx.x;  // 0..255
    Wt[n * FIN + k] = f2bf(W[k * FOUT + n]);
}

// ---------------------------------------------------------------------------
// KA: WhT[b][d][j] = (x@W)^T via MFMA + fused f1/f2 = Wh.a1 / Wh.a2.
// 32 j-rows/block, 512 blocks. A-frags from global Wt (L2-hot).
// WhT stores coalesced via LDS transpose tile.  (unchanged)
// ---------------------------------------------------------------------------
__global__ __launch_bounds__(256) void ka_wh(const float* __restrict__ x,
                                             const unsigned short* __restrict__ Wt,
                                             const float* __restrict__ a,
                                             unsigned short* __restrict__ WhT,
                                             float* __restrict__ f1,
                                             float* __restrict__ f2) {
    __shared__ unsigned short xs[32 * XR];   // 16.5 KB; reused as T[128][TR]
    __shared__ float as[2 * FOUT];           // 1 KB
    __shared__ float fred[2][4][32];         // 1 KB

    const int tid = threadIdx.x;
    const int j0  = blockIdx.x * 32;         // global flat row base
    const int b   = j0 >> 11;
    const int jb  = j0 & (N_ - 1);

    if (tid < 2 * FOUT) as[tid] = a[tid];
    {   // stage 32 x-rows (fp32 -> bf16), coalesced 32 KB read
        const float4* xsrc = (const float4*)(x + (size_t)j0 * FIN);
#pragma unroll
        for (int t = 0; t < 8; ++t) {
            const int idx = tid + t * 256;
            float4 v = xsrc[idx];
            const int row = idx >> 6, c4 = idx & 63;
            ushort4 u;
            u.x = f2bf(v.x); u.y = f2bf(v.y); u.z = f2bf(v.z); u.w = f2bf(v.w);
            *(ushort4*)&xs[row * XR + c4 * 4] = u;
        }
    }
    __syncthreads();

    const int wave = tid >> 6, lane = tid & 63;
    const int quad = lane >> 4, l16 = lane & 15;

    f32x4 acc[2][2];  // [a-tile(d)][n-tile(j)]
#pragma unroll
    for (int aa = 0; aa < 2; ++aa)
#pragma unroll
        for (int nn = 0; nn < 2; ++nn) acc[aa][nn] = {0.f, 0.f, 0.f, 0.f};

    const unsigned short* wtA0 = Wt + (size_t)(32 * wave + l16) * FIN;
    const unsigned short* wtA1 = wtA0 + 16 * FIN;
#pragma unroll
    for (int ks = 0; ks < FIN / 32; ++ks) {
        const int kof = ks * 32 + quad * 8;
        bf16x8 af0 = *(const bf16x8*)&wtA0[kof];
        bf16x8 af1 = *(const bf16x8*)&wtA1[kof];
        bf16x8 bf0 = *(const bf16x8*)&xs[l16 * XR + kof];
        bf16x8 bf1 = *(const bf16x8*)&xs[(16 + l16) * XR + kof];
        acc[0][0] = __builtin_amdgcn_mfma_f32_16x16x32_bf16(af0, bf0, acc[0][0], 0, 0, 0);
        acc[0][1] = __builtin_amdgcn_mfma_f32_16x16x32_bf16(af0, bf1, acc[0][1], 0, 0, 0);
        acc[1][0] = __builtin_amdgcn_mfma_f32_16x16x32_bf16(af1, bf0, acc[1][0], 0, 0, 0);
        acc[1][1] = __builtin_amdgcn_mfma_f32_16x16x32_bf16(af1, bf1, acc[1][1], 0, 0, 0);
    }
    __syncthreads();   // xs dead; safe to reuse as transpose tile T

    unsigned short* T = xs;   // [128][TR]
    float pf[2][2] = {{0.f, 0.f}, {0.f, 0.f}};  // [f1/f2][n-tile]
#pragma unroll
    for (int aa = 0; aa < 2; ++aa)
#pragma unroll
        for (int nn = 0; nn < 2; ++nn)
#pragma unroll
            for (int r = 0; r < 4; ++r) {
                const int d = 32 * wave + 16 * aa + 4 * quad + r;
                const float v = acc[aa][nn][r];
                T[d * TR + nn * 16 + l16] = f2bf(v);
                pf[0][nn] += v * as[d];
                pf[1][nn] += v * as[FOUT + d];
            }
#pragma unroll
    for (int ff = 0; ff < 2; ++ff)
#pragma unroll
        for (int nn = 0; nn < 2; ++nn) {
            float v = pf[ff][nn];
            v += __shfl_xor(v, 16);
            v += __shfl_xor(v, 32);
            pf[ff][nn] = v;
        }
    if (quad == 0) {
#pragma unroll
        for (int ff = 0; ff < 2; ++ff)
#pragma unroll
            for (int nn = 0; nn < 2; ++nn)
                fred[ff][wave][nn * 16 + l16] = pf[ff][nn];
    }
    __syncthreads();

    unsigned short* dstW = WhT + (size_t)b * FOUT * N_;
#pragma unroll
    for (int it = 0; it < 2; ++it) {
        const int idx = it * 256 + tid;
        const int d = idx >> 2, q = idx & 3;
        bf16x8 v = *(const bf16x8*)&T[d * TR + q * 8];
        *(bf16x8*)&dstW[(size_t)d * N_ + jb + q * 8] = v;
    }
    if (tid < 64) {
        const int ff = tid >> 5, j32 = tid & 31;
        const float s = fred[ff][0][j32] + fred[ff][1][j32] +
                        fred[ff][2][j32] + fred[ff][3][j32];
        (ff ? f2 : f1)[(size_t)b * N_ + jb + j32] = s;
    }
}

// ---------------------------------------------------------------------------
// KB: fused masked softmax + P@WhT (MFMA) + ELU.
// RESTRUCTURED for latency hiding (old version: VGPR=52, everything idle,
// latency-bound at 84 us):
//   * 512 threads / 8 waves per block. Each wave: 2 adj rows in phase A,
//     one 16-col n-tile in phase B (16 MFMAs/chunk -> WhT chunk fits in
//     16 bf16x8 regs).
//   * Per chunk iteration, vmem ISSUE ORDER is chosen around in-order vmcnt
//     retire: [16x WhT frag loads (L2-hot, oldest)] -> [f2 vec] -> [4x adj
//     nt-loads (HBM, youngest)]. The MFMA loop then waits only counted
//     vmcnt against WhT frags, while the adj loads stay in flight under the
//     whole MFMA phase; PROCESS consumes them afterwards (T14 split).
//   * __launch_bounds__(512,4) caps VGPR at 128 (br[16]=64 + areg 16 + fv 8
//     + acc 4 + misc) -> 2 blocks/CU, 16 waves/CU.
// Numerics identical to previous version (same accumulation order).
// ---------------------------------------------------------------------------
__global__ __launch_bounds__(512, 4) void kb_attn(const int* __restrict__ adj,
                                                  const unsigned short* __restrict__ WhT,
                                                  const float* __restrict__ f1,
                                                  const float* __restrict__ f2,
                                                  float* __restrict__ out) {
    __shared__ unsigned short p[2][16 * PR];  // 33.3 KB
    __shared__ float rsum[16];

    const int tid  = threadIdx.x;
    const int b    = blockIdx.x & 7;          // XCD-pinned batch
    const int i0   = (blockIdx.x >> 3) * 16;
    const int wave = tid >> 6, lane = tid & 63;  // wave 0..7
    const int quad = lane >> 4, l16 = lane & 15;

    const float4* f2b4 = (const float4*)(f2 + (size_t)b * N_);
    const int*    adjB = adj + (size_t)b * N_ * N_;

    float f1r[2], s_run[2];
#pragma unroll
    for (int rr = 0; rr < 2; ++rr) {
        f1r[rr]   = f1[(size_t)b * N_ + i0 + wave * 2 + rr];
        s_run[rr] = 0.f;
    }

    f32x4 acc = {0.f, 0.f, 0.f, 0.f};
    const unsigned short* wBr =
        WhT + (size_t)b * FOUT * N_ + (size_t)(wave * 16 + l16) * N_;

    i32x4  areg[2][2];   // in-flight adj for chunk c+1: [row rr][half]
    float4 fv[2];        // in-flight f2 for chunk c+1

    // Issue loads for chunk c: f2 first (L2-hot), then adj (HBM nt).
    auto LOADS = [&](int c) {
        fv[0] = f2b4[c * (CH / 4) + lane];
        fv[1] = f2b4[c * (CH / 4) + 64 + lane];
#pragma unroll
        for (int rr = 0; rr < 2; ++rr) {
            const int* arow =
                adjB + (size_t)(i0 + wave * 2 + rr) * N_ + c * CH;
            areg[rr][0] = ntload4(arow + 4 * lane);
            areg[rr][1] = ntload4(arow + 256 + 4 * lane);
        }
    };

    // Consume areg/fv for chunk c: leaky-relu, mask, exp, rowsum, pack->LDS.
    auto PROCESS = [&](int c) {
        unsigned short* pb = &p[c & 1][0];
#pragma unroll
        for (int rr = 0; rr < 2; ++rr) {
            const int ti = wave * 2 + rr;
            const float f1i = f1r[rr];
            const i32x4 av0 = areg[rr][0];
            const i32x4 av1 = areg[rr][1];

            float e[8];
            e[0] = f1i + fv[0].x; e[1] = f1i + fv[0].y;
            e[2] = f1i + fv[0].z; e[3] = f1i + fv[0].w;
            e[4] = f1i + fv[1].x; e[5] = f1i + fv[1].y;
            e[6] = f1i + fv[1].z; e[7] = f1i + fv[1].w;
#pragma unroll
            for (int q = 0; q < 8; ++q) e[q] = (e[q] >= 0.f) ? e[q] : 2.f * e[q];

            float pv[8];
            pv[0] = (av0.x > 0) ? __expf(e[0]) : 0.f;
            pv[1] = (av0.y > 0) ? __expf(e[1]) : 0.f;
            pv[2] = (av0.z > 0) ? __expf(e[2]) : 0.f;
            pv[3] = (av0.w > 0) ? __expf(e[3]) : 0.f;
            pv[4] = (av1.x > 0) ? __expf(e[4]) : 0.f;
            pv[5] = (av1.y > 0) ? __expf(e[5]) : 0.f;
            pv[6] = (av1.z > 0) ? __expf(e[6]) : 0.f;
            pv[7] = (av1.w > 0) ? __expf(e[7]) : 0.f;

            s_run[rr] += ((pv[0] + pv[1]) + (pv[2] + pv[3])) +
                         ((pv[4] + pv[5]) + (pv[6] + pv[7]));

            ushort4 u0, u1;
            u0.x = f2bf(pv[0]); u0.y = f2bf(pv[1]);
            u0.z = f2bf(pv[2]); u0.w = f2bf(pv[3]);
            u1.x = f2bf(pv[4]); u1.y = f2bf(pv[5]);
            u1.z = f2bf(pv[6]); u1.w = f2bf(pv[7]);
            *(ushort4*)&pb[ti * PR + 4 * lane]       = u0;
            *(ushort4*)&pb[ti * PR + 256 + 4 * lane] = u1;
        }
    };

    // Prologue: stage chunk 0 (adj latency exposed once).
    LOADS(0);
    PROCESS(0);
    __syncthreads();

    for (int c = 0; c < NCH; ++c) {
        // 1) Preload FULL WhT chunk for this wave's n-tile BEFORE issuing the
        //    slow adj loads: these are the oldest vmem ops of the iteration,
        //    so the MFMA loop's counted vmcnt waits never couple to adj.
        const unsigned short* wBc = wBr + (size_t)c * CH;
        bf16x8 br[16];
#pragma unroll
        for (int ks = 0; ks < CH / 32; ++ks)
            br[ks] = *(const bf16x8*)&wBc[ks * 32 + quad * 8];

        // 2) Issue next chunk's f2 + adj loads; they fly under the MFMAs.
        if (c + 1 < NCH) LOADS(c + 1);

        // 3) MFMA phase: pure LDS-read + register MFMA against br[].
        const unsigned short* pA = &p[c & 1][l16 * PR];
#pragma unroll
        for (int ks = 0; ks < CH / 32; ++ks) {
            bf16x8 afr = *(const bf16x8*)&pA[ks * 32 + quad * 8];
            acc = __builtin_amdgcn_mfma_f32_16x16x32_bf16(afr, br[ks], acc,
                                                          0, 0, 0);
        }

        // 4) Consume the prefetched chunk (adj latency now amortized), or on
        //    the last chunk finalize the row sums.
        if (c + 1 < NCH) {
            PROCESS(c + 1);
        } else {
#pragma unroll
            for (int rr = 0; rr < 2; ++rr) {
                float s = s_run[rr];
#pragma unroll
                for (int o = 32; o; o >>= 1) s += __shfl_xor(s, o);
                if (lane == 0) rsum[wave * 2 + rr] = s;
            }
        }
        __syncthreads();
    }

    // ---- Epilogue: /rowsum, ELU, store (row m = quad*4+r, col = l16) ----
#pragma unroll
    for (int r = 0; r < 4; ++r) {
        const int m = quad * 4 + r;
        const float inv = 1.f / rsum[m];
        float v = acc[r] * inv;
        v = (v > 0.f) ? v : expm1f(v);
        out[((size_t)b * N_ + i0 + m) * FOUT + wave * 16 + l16] = v;
    }
}

// ---------------------------------------------------------------------------
extern "C" void kernel_launch(void* const* d_in, const int* in_sizes, int n_in,
                              void* d_out, int out_size, void* d_ws, size_t ws_size,
                              hipStream_t stream) {
    const float* x   = (const float*)d_in[0];
    const int*   adj = (const int*)d_in[1];
    const float* W   = (const float*)d_in[2];
    const float* a   = (const float*)d_in[3];
    float* out = (float*)d_out;

    // ws: WhT bf16 (4 MB) | Wt bf16 (64 KB) | f1 (64 KB) | f2 (64 KB)
    unsigned short* WhT = (unsigned short*)d_ws;
    unsigned short* Wt  = WhT + (size_t)B_ * FOUT * N_;
    float* f1 = (float*)(Wt + (size_t)FOUT * FIN);
    float* f2 = f1 + (size_t)B_ * N_;

    hipLaunchKernelGGL(k0_wt, dim3(FOUT), dim3(FIN), 0, stream, W, Wt);
    hipLaunchKernelGGL(ka_wh, dim3(B_ * N_ / 32), dim3(256), 0, stream,
                       x, Wt, a, WhT, f1, f2);
    hipLaunchKernelGGL(kb_attn, dim3(B_ * N_ / 16), dim3(512), 0, stream,
                       adj, WhT, f1, f2, out);
}

// Round 3
// 259.473 us; speedup vs baseline: 1.0027x; 1.0027x over previous
//
#include <hip/hip_runtime.h>
#include <hip/hip_bf16.h>
#include <math.h>

constexpr int B_   = 8;
constexpr int N_   = 2048;
constexpr int FIN  = 256;
constexpr int FOUT = 128;

constexpr int CH  = 512;          // KB K-chunk length
constexpr int NCH = N_ / CH;      // 4 chunks
constexpr int PR  = CH + 8;       // 520 shorts per P row (pad)
constexpr int XR  = FIN + 8;      // 264 shorts per xs row (pad)
constexpr int TR  = 40;           // ka transpose-tile row stride (32 j + 8 pad)

typedef __attribute__((ext_vector_type(8))) short bf16x8;
typedef __attribute__((ext_vector_type(4))) float f32x4;
typedef __attribute__((ext_vector_type(4))) int   i32x4;

static __device__ __forceinline__ unsigned short f2bf(float f) {
    __hip_bfloat16 h = __float2bfloat16(f);
    return *reinterpret_cast<unsigned short*>(&h);
}
static __device__ __forceinline__ i32x4 ntload4(const int* p) {
    return __builtin_nontemporal_load((const i32x4*)p);
}

// ---------------------------------------------------------------------------
// K0: Wt[n][k] = bf16(W[k][n])  (dim-major weight, 64 KB). Tiny.
// ---------------------------------------------------------------------------
__global__ __launch_bounds__(256) void k0_wt(const float* __restrict__ W,
                                             unsigned short* __restrict__ Wt) {
    const int n = blockIdx.x;   // 0..127
    const int k = threadIdx.x;  // 0..255
    Wt[n * FIN + k] = f2bf(W[k * FOUT + n]);
}

// ---------------------------------------------------------------------------
// KA: WhT[b][d][j] = (x@W)^T via MFMA + fused f1/f2 = Wh.a1 / Wh.a2.
// 32 j-rows/block, 512 blocks. A-frags from global Wt (L2-hot).
// WhT stores coalesced via LDS transpose tile.  (unchanged)
// ---------------------------------------------------------------------------
__global__ __launch_bounds__(256) void ka_wh(const float* __restrict__ x,
                                             const unsigned short* __restrict__ Wt,
                                             const float* __restrict__ a,
                                             unsigned short* __restrict__ WhT,
                                             float* __restrict__ f1,
                                             float* __restrict__ f2) {
    __shared__ unsigned short xs[32 * XR];   // 16.5 KB; reused as T[128][TR]
    __shared__ float as[2 * FOUT];           // 1 KB
    __shared__ float fred[2][4][32];         // 1 KB

    const int tid = threadIdx.x;
    const int j0  = blockIdx.x * 32;         // global flat row base
    const int b   = j0 >> 11;
    const int jb  = j0 & (N_ - 1);

    if (tid < 2 * FOUT) as[tid] = a[tid];
    {   // stage 32 x-rows (fp32 -> bf16), coalesced 32 KB read
        const float4* xsrc = (const float4*)(x + (size_t)j0 * FIN);
#pragma unroll
        for (int t = 0; t < 8; ++t) {
            const int idx = tid + t * 256;
            float4 v = xsrc[idx];
            const int row = idx >> 6, c4 = idx & 63;
            ushort4 u;
            u.x = f2bf(v.x); u.y = f2bf(v.y); u.z = f2bf(v.z); u.w = f2bf(v.w);
            *(ushort4*)&xs[row * XR + c4 * 4] = u;
        }
    }
    __syncthreads();

    const int wave = tid >> 6, lane = tid & 63;
    const int quad = lane >> 4, l16 = lane & 15;

    f32x4 acc[2][2];  // [a-tile(d)][n-tile(j)]
#pragma unroll
    for (int aa = 0; aa < 2; ++aa)
#pragma unroll
        for (int nn = 0; nn < 2; ++nn) acc[aa][nn] = {0.f, 0.f, 0.f, 0.f};

    const unsigned short* wtA0 = Wt + (size_t)(32 * wave + l16) * FIN;
    const unsigned short* wtA1 = wtA0 + 16 * FIN;
#pragma unroll
    for (int ks = 0; ks < FIN / 32; ++ks) {
        const int kof = ks * 32 + quad * 8;
        bf16x8 af0 = *(const bf16x8*)&wtA0[kof];
        bf16x8 af1 = *(const bf16x8*)&wtA1[kof];
        bf16x8 bf0 = *(const bf16x8*)&xs[l16 * XR + kof];
        bf16x8 bf1 = *(const bf16x8*)&xs[(16 + l16) * XR + kof];
        acc[0][0] = __builtin_amdgcn_mfma_f32_16x16x32_bf16(af0, bf0, acc[0][0], 0, 0, 0);
        acc[0][1] = __builtin_amdgcn_mfma_f32_16x16x32_bf16(af0, bf1, acc[0][1], 0, 0, 0);
        acc[1][0] = __builtin_amdgcn_mfma_f32_16x16x32_bf16(af1, bf0, acc[1][0], 0, 0, 0);
        acc[1][1] = __builtin_amdgcn_mfma_f32_16x16x32_bf16(af1, bf1, acc[1][1], 0, 0, 0);
    }
    __syncthreads();   // xs dead; safe to reuse as transpose tile T

    unsigned short* T = xs;   // [128][TR]
    float pf[2][2] = {{0.f, 0.f}, {0.f, 0.f}};  // [f1/f2][n-tile]
#pragma unroll
    for (int aa = 0; aa < 2; ++aa)
#pragma unroll
        for (int nn = 0; nn < 2; ++nn)
#pragma unroll
            for (int r = 0; r < 4; ++r) {
                const int d = 32 * wave + 16 * aa + 4 * quad + r;
                const float v = acc[aa][nn][r];
                T[d * TR + nn * 16 + l16] = f2bf(v);
                pf[0][nn] += v * as[d];
                pf[1][nn] += v * as[FOUT + d];
            }
#pragma unroll
    for (int ff = 0; ff < 2; ++ff)
#pragma unroll
        for (int nn = 0; nn < 2; ++nn) {
            float v = pf[ff][nn];
            v += __shfl_xor(v, 16);
            v += __shfl_xor(v, 32);
            pf[ff][nn] = v;
        }
    if (quad == 0) {
#pragma unroll
        for (int ff = 0; ff < 2; ++ff)
#pragma unroll
            for (int nn = 0; nn < 2; ++nn)
                fred[ff][wave][nn * 16 + l16] = pf[ff][nn];
    }
    __syncthreads();

    unsigned short* dstW = WhT + (size_t)b * FOUT * N_;
#pragma unroll
    for (int it = 0; it < 2; ++it) {
        const int idx = it * 256 + tid;
        const int d = idx >> 2, q = idx & 3;
        bf16x8 v = *(const bf16x8*)&T[d * TR + q * 8];
        *(bf16x8*)&dstW[(size_t)d * N_ + jb + q * 8] = v;
    }
    if (tid < 64) {
        const int ff = tid >> 5, j32 = tid & 31;
        const float s = fred[ff][0][j32] + fred[ff][1][j32] +
                        fred[ff][2][j32] + fred[ff][3][j32];
        (ff ? f2 : f1)[(size_t)b * N_ + jb + j32] = s;
    }
}

// ---------------------------------------------------------------------------
// KB: fused masked softmax + P@WhT (MFMA) + ELU.
// Round-1 finding: the restructure was silently undone by the compiler
// (VGPR_Count stayed 52 -> br[16] never materialized; loads re-sunk into
// the MFMA loop -> identical 84 us latency-serialized schedule).
// Round-2 fix attempt died on compile: "+v" inline-asm pins on HIP float4
// (a STRUCT) are "tied indirect register inputs". This round uses
// ext_vector f32x4 for the pinned f2 value (register-typed, pinnable).
// Forced schedule:
//   * asm volatile("" : "+v"(reg)) keep-alive pins after each load group:
//     all 16 WhT fragment loads must issue before any MFMA, and stay
//     register-resident (compiler cannot sink/remat them).
//   * sched_barrier(0) fences fix program order = vmem issue order:
//     [16x br (L2-hot, oldest)] -> [f2 + 4x adj nt (HBM, youngest)] ->
//     [MFMA loop: backend emits counted vmcnt, adj stays in flight] ->
//     [PROCESS consumes adj after MFMA].
// Expected: VGPR ~110-135 (proof of materialization), kb 84 -> 35-55 us.
// Numerics identical to previous passing version (same accumulation order).
// ---------------------------------------------------------------------------
__global__ __launch_bounds__(512, 4) void kb_attn(const int* __restrict__ adj,
                                                  const unsigned short* __restrict__ WhT,
                                                  const float* __restrict__ f1,
                                                  const float* __restrict__ f2,
                                                  float* __restrict__ out) {
    __shared__ unsigned short p[2][16 * PR];  // 33.3 KB
    __shared__ float rsum[16];

    const int tid  = threadIdx.x;
    const int b    = blockIdx.x & 7;          // XCD-pinned batch
    const int i0   = (blockIdx.x >> 3) * 16;
    const int wave = tid >> 6, lane = tid & 63;  // wave 0..7
    const int quad = lane >> 4, l16 = lane & 15;

    const f32x4* f2b4 = (const f32x4*)(f2 + (size_t)b * N_);
    const int*   adjB = adj + (size_t)b * N_ * N_;

    float f1r[2], s_run[2];
#pragma unroll
    for (int rr = 0; rr < 2; ++rr) {
        f1r[rr]   = f1[(size_t)b * N_ + i0 + wave * 2 + rr];
        s_run[rr] = 0.f;
    }

    f32x4 acc = {0.f, 0.f, 0.f, 0.f};
    const unsigned short* wBr =
        WhT + (size_t)b * FOUT * N_ + (size_t)(wave * 16 + l16) * N_;

    i32x4 areg[2][2];   // in-flight adj for next chunk: [row rr][half]
    f32x4 fv[2];        // in-flight f2 for next chunk (ext_vector: pinnable)

    // Issue loads for chunk c: f2 first (L2-hot), then adj (HBM nt).
    auto LOADS = [&](int c) {
        fv[0] = f2b4[c * (CH / 4) + lane];
        fv[1] = f2b4[c * (CH / 4) + 64 + lane];
#pragma unroll
        for (int rr = 0; rr < 2; ++rr) {
            const int* arow =
                adjB + (size_t)(i0 + wave * 2 + rr) * N_ + c * CH;
            areg[rr][0] = ntload4(arow + 4 * lane);
            areg[rr][1] = ntload4(arow + 256 + 4 * lane);
        }
    };

    // Pin the in-flight loads so the compiler cannot sink them into PROCESS.
    auto PIN_LOADS = [&]() {
        asm volatile("" : "+v"(fv[0]), "+v"(fv[1]));
#pragma unroll
        for (int rr = 0; rr < 2; ++rr)
            asm volatile("" : "+v"(areg[rr][0]), "+v"(areg[rr][1]));
    };

    // Consume areg/fv for chunk c: leaky-relu, mask, exp, rowsum, pack->LDS.
    auto PROCESS = [&](int c) {
        unsigned short* pb = &p[c & 1][0];
#pragma unroll
        for (int rr = 0; rr < 2; ++rr) {
            const int ti = wave * 2 + rr;
            const float f1i = f1r[rr];
            const i32x4 av0 = areg[rr][0];
            const i32x4 av1 = areg[rr][1];

            float e[8];
            e[0] = f1i + fv[0][0]; e[1] = f1i + fv[0][1];
            e[2] = f1i + fv[0][2]; e[3] = f1i + fv[0][3];
            e[4] = f1i + fv[1][0]; e[5] = f1i + fv[1][1];
            e[6] = f1i + fv[1][2]; e[7] = f1i + fv[1][3];
#pragma unroll
            for (int q = 0; q < 8; ++q) e[q] = (e[q] >= 0.f) ? e[q] : 2.f * e[q];

            float pv[8];
            pv[0] = (av0[0] > 0) ? __expf(e[0]) : 0.f;
            pv[1] = (av0[1] > 0) ? __expf(e[1]) : 0.f;
            pv[2] = (av0[2] > 0) ? __expf(e[2]) : 0.f;
            pv[3] = (av0[3] > 0) ? __expf(e[3]) : 0.f;
            pv[4] = (av1[0] > 0) ? __expf(e[4]) : 0.f;
            pv[5] = (av1[1] > 0) ? __expf(e[5]) : 0.f;
            pv[6] = (av1[2] > 0) ? __expf(e[6]) : 0.f;
            pv[7] = (av1[3] > 0) ? __expf(e[7]) : 0.f;

            s_run[rr] += ((pv[0] + pv[1]) + (pv[2] + pv[3])) +
                         ((pv[4] + pv[5]) + (pv[6] + pv[7]));

            ushort4 u0, u1;
            u0.x = f2bf(pv[0]); u0.y = f2bf(pv[1]);
            u0.z = f2bf(pv[2]); u0.w = f2bf(pv[3]);
            u1.x = f2bf(pv[4]); u1.y = f2bf(pv[5]);
            u1.z = f2bf(pv[6]); u1.w = f2bf(pv[7]);
            *(ushort4*)&pb[ti * PR + 4 * lane]       = u0;
            *(ushort4*)&pb[ti * PR + 256 + 4 * lane] = u1;
        }
    };

    // Prologue: stage chunk 0 (adj latency exposed once).
    LOADS(0);
    PROCESS(0);
    __syncthreads();

    for (int c = 0; c < NCH; ++c) {
        // 1) Issue ALL 16 WhT fragment loads for this wave's n-tile. The
        //    keep-alive pins force: (a) every load issued before any MFMA,
        //    (b) all 16 results simultaneously register-resident.
        const unsigned short* wBc = wBr + (size_t)c * CH;
        bf16x8 br[16];
#pragma unroll
        for (int ks = 0; ks < CH / 32; ++ks)
            br[ks] = *(const bf16x8*)&wBc[ks * 32 + quad * 8];
#pragma unroll
        for (int ks = 0; ks < CH / 32; ++ks)
            asm volatile("" : "+v"(br[ks]));
        __builtin_amdgcn_sched_barrier(0);

        // 2) Issue next chunk's f2 + adj loads AFTER br in program order:
        //    in-order vmcnt retire => the MFMA loop's wait for br is a
        //    counted vmcnt; adj stays in flight under all the MFMAs.
        if (c + 1 < NCH) {
            LOADS(c + 1);
            PIN_LOADS();
        }
        __builtin_amdgcn_sched_barrier(0);

        // 3) MFMA phase: LDS-read A-fragments + register MFMA against br[].
        const unsigned short* pA = &p[c & 1][l16 * PR];
#pragma unroll
        for (int ks = 0; ks < CH / 32; ++ks) {
            bf16x8 afr = *(const bf16x8*)&pA[ks * 32 + quad * 8];
            acc = __builtin_amdgcn_mfma_f32_16x16x32_bf16(afr, br[ks], acc,
                                                          0, 0, 0);
        }
        __builtin_amdgcn_sched_barrier(0);

        // 4) Consume the prefetched chunk (adj latency amortized under MFMA),
        //    or on the last chunk finalize the row sums.
        if (c + 1 < NCH) {
            PROCESS(c + 1);
        } else {
#pragma unroll
            for (int rr = 0; rr < 2; ++rr) {
                float s = s_run[rr];
#pragma unroll
                for (int o = 32; o; o >>= 1) s += __shfl_xor(s, o);
                if (lane == 0) rsum[wave * 2 + rr] = s;
            }
        }
        __syncthreads();
    }

    // ---- Epilogue: /rowsum, ELU, store (row m = quad*4+r, col = l16) ----
#pragma unroll
    for (int r = 0; r < 4; ++r) {
        const int m = quad * 4 + r;
        const float inv = 1.f / rsum[m];
        float v = acc[r] * inv;
        v = (v > 0.f) ? v : expm1f(v);
        out[((size_t)b * N_ + i0 + m) * FOUT + wave * 16 + l16] = v;
    }
}

// ---------------------------------------------------------------------------
extern "C" void kernel_launch(void* const* d_in, const int* in_sizes, int n_in,
                              void* d_out, int out_size, void* d_ws, size_t ws_size,
                              hipStream_t stream) {
    const float* x   = (const float*)d_in[0];
    const int*   adj = (const int*)d_in[1];
    const float* W   = (const float*)d_in[2];
    const float* a   = (const float*)d_in[3];
    float* out = (float*)d_out;

    // ws: WhT bf16 (4 MB) | Wt bf16 (64 KB) | f1 (64 KB) | f2 (64 KB)
    unsigned short* WhT = (unsigned short*)d_ws;
    unsigned short* Wt  = WhT + (size_t)B_ * FOUT * N_;
    float* f1 = (float*)(Wt + (size_t)FOUT * FIN);
    float* f2 = f1 + (size_t)B_ * N_;

    hipLaunchKernelGGL(k0_wt, dim3(FOUT), dim3(FIN), 0, stream, W, Wt);
    hipLaunchKernelGGL(ka_wh, dim3(B_ * N_ / 32), dim3(256), 0, stream,
                       x, Wt, a, WhT, f1, f2);
    hipLaunchKernelGGL(kb_attn, dim3(B_ * N_ / 16), dim3(512), 0, stream,
                       adj, WhT, f1, f2, out);
}